// Round 4
// baseline (117.947 us; speedup 1.0000x reference)
//
#include <hip/hip_runtime.h>

#define PI_F 3.14159265358979323846f

typedef float v2f __attribute__((ext_vector_type(2)));

__device__ __forceinline__ void pkfma(v2f& d, v2f a, v2f b) {
    asm("v_pk_fma_f32 %0, %1, %2, %0" : "+v"(d) : "v"(a), "v"(b));
}

// ---------------- K1: conv1 7x7 (4->8) + maxpool 2x2 + bias + relu ----------------
// x:(8,4,128,128,8) -> h1:(8,8,61,61,8).
// Tile: 8x4 pooled. thread = (pos32, cp4, wq2[4w]). acc pairs over oc: v2f[4][4].
// Weights in LDS [ic][tap][oc] (broadcast b128); input staged with T14 prefetch.
__global__ __launch_bounds__(256, 6) void k_conv1(const float* __restrict__ x,
                                                  const float* __restrict__ w1,
                                                  const float* __restrict__ b1,
                                                  float* __restrict__ h1) {
    const int b = blockIdx.y;
    const int ty = blockIdx.x >> 4, tx = blockIdx.x & 15;   // 8 x 16 tiles
    const int py0 = ty * 8, px0 = tx * 4;
    const int iy0 = py0 * 2, ix0 = px0 * 2;

    __shared__ float tin[22 * 14 * 8];     // 9856 B
    __shared__ float wl[4 * 49 * 8];       // 6272 B  [ic][tap][oc]

    const int tid = threadIdx.x;
    // transpose w1 (oc,ic,tap) -> wl[ic][tap][oc]
    for (int i = tid; i < 1568; i += 256) {
        const int oc = i / 196, rem = i % 196;        // rem = ic*49+tap
        wl[rem * 8 + oc] = w1[i];
    }

    const int wq = tid & 1;                // 4 w each
    const int cp = (tid >> 1) & 3;         // conv pos in 2x2 pool window
    const int pp = tid >> 3;               // 0..31 (8 rows x 4 cols pooled)
    const int pl = pp >> 2, pj = pp & 3;
    const int cy = 2 * pl + (cp >> 1), cx = 2 * pj + (cp & 1);

    // staging addresses (fixed per thread, 3 slots; clamped rows/cols only feed
    // conv positions >=122 which are discarded by the pi/pjg<61 store guard)
    int sIdx[3];
    sIdx[0] = tid; sIdx[1] = tid + 256; sIdx[2] = (tid + 512 < 616) ? tid + 512 : 615;
    const bool s2act = (tid + 512 < 616);
    size_t sOff[3];
#pragma unroll
    for (int s = 0; s < 3; ++s) {
        const int r = sIdx[s] / 28, c4 = sIdx[s] % 28;
        const int row = min(iy0 + r, 127), col = min(ix0 + (c4 >> 1), 127);
        sOff[s] = ((size_t)row * 128 + col) * 8 + (c4 & 1) * 4;
    }

    v2f acc[4][4];   // [oc pair][w]
#pragma unroll
    for (int p = 0; p < 4; ++p)
#pragma unroll
        for (int w = 0; w < 4; ++w) acc[p][w] = (v2f)(0.f);

    float4 r0, r1, r2;
    {   // prologue: stage ic=0
        const float* xb = x + (size_t)b * 4 * 131072;
        r0 = *reinterpret_cast<const float4*>(xb + sOff[0]);
        r1 = *reinterpret_cast<const float4*>(xb + sOff[1]);
        r2 = *reinterpret_cast<const float4*>(xb + sOff[2]);
        *reinterpret_cast<float4*>(&tin[sIdx[0] * 4]) = r0;
        *reinterpret_cast<float4*>(&tin[sIdx[1] * 4]) = r1;
        if (s2act) *reinterpret_cast<float4*>(&tin[sIdx[2] * 4]) = r2;
    }
    __syncthreads();   // covers wl + tin(ic=0)

    for (int ic = 0; ic < 4; ++ic) {
        if (ic < 3) {  // prefetch next ic into registers (overlaps compute below)
            const float* xb = x + ((size_t)b * 4 + ic + 1) * 131072;
            r0 = *reinterpret_cast<const float4*>(xb + sOff[0]);
            r1 = *reinterpret_cast<const float4*>(xb + sOff[1]);
            r2 = *reinterpret_cast<const float4*>(xb + sOff[2]);
        }
        for (int kd = 0; kd < 7; ++kd) {
            const float* vrow = &tin[((cy + kd) * 14 + cx) * 8 + wq * 4];
            const float* wrow = &wl[(ic * 49 + kd * 7) * 8];
#pragma unroll
            for (int kh = 0; kh < 7; ++kh) {
                const float4 v  = *reinterpret_cast<const float4*>(&vrow[kh * 8]);
                const float4 wa = *reinterpret_cast<const float4*>(&wrow[kh * 8]);
                const float4 wb = *reinterpret_cast<const float4*>(&wrow[kh * 8 + 4]);
                v2f wp[4];
                wp[0] = (v2f){wa.x, wa.y}; wp[1] = (v2f){wa.z, wa.w};
                wp[2] = (v2f){wb.x, wb.y}; wp[3] = (v2f){wb.z, wb.w};
                const float vv[4] = {v.x, v.y, v.z, v.w};
#pragma unroll
                for (int w = 0; w < 4; ++w) {
                    const v2f sv = (v2f){vv[w], vv[w]};
#pragma unroll
                    for (int p = 0; p < 4; ++p) pkfma(acc[p][w], wp[p], sv);
                }
            }
        }
        if (ic < 3) {
            __syncthreads();
            *reinterpret_cast<float4*>(&tin[sIdx[0] * 4]) = r0;
            *reinterpret_cast<float4*>(&tin[sIdx[1] * 4]) = r1;
            if (s2act) *reinterpret_cast<float4*>(&tin[sIdx[2] * 4]) = r2;
            __syncthreads();
        }
    }

    const int pi = py0 + pl, pjg = px0 + pj;
    const bool doStore = (cp == 0) && (pi < 61) && (pjg < 61);
#pragma unroll
    for (int p = 0; p < 4; ++p) {
        const float be = b1[2 * p], bo = b1[2 * p + 1];
        float e[4], o[4];
#pragma unroll
        for (int w = 0; w < 4; ++w) {
            float a = acc[p][w].x, c = acc[p][w].y;
            a = fmaxf(a, __shfl_xor(a, 2)); a = fmaxf(a, __shfl_xor(a, 4));
            c = fmaxf(c, __shfl_xor(c, 2)); c = fmaxf(c, __shfl_xor(c, 4));
            e[w] = fmaxf(a + be, 0.f);
            o[w] = fmaxf(c + bo, 0.f);
        }
        if (doStore) {
            *reinterpret_cast<float4*>(
                h1 + ((((size_t)b * 8 + 2 * p) * 61 + pi) * 61 + pjg) * 8 + wq * 4) =
                make_float4(e[0], e[1], e[2], e[3]);
            *reinterpret_cast<float4*>(
                h1 + ((((size_t)b * 8 + 2 * p + 1) * 61 + pi) * 61 + pjg) * 8 + wq * 4) =
                make_float4(o[0], o[1], o[2], o[3]);
        }
    }
}

// ---------------- K2: conv2 5x5 (8->10) + maxpool 2x2 + bias + relu ----------------
// h1:(8,8,61,61,8) -> h2:(8,10,28,28,8).
// Tile: 2x4 pooled. thread = (pos8, cp4, w8). acc pairs over oc: v2f[5].
__global__ __launch_bounds__(256, 8) void k_conv2(const float* __restrict__ h1,
                                                  const float* __restrict__ w2,
                                                  const float* __restrict__ b2,
                                                  float* __restrict__ h2) {
    const int b = blockIdx.y;
    const int ty = blockIdx.x / 7, tx = blockIdx.x % 7;    // 14 x 7 tiles
    const int py0 = ty * 2, px0 = tx * 4;
    const int iy0 = py0 * 2, ix0 = px0 * 2;

    __shared__ float tin[8 * 12 * 8];      // 3072 B
    __shared__ float wl[8 * 25 * 12];      // 9600 B  [ic][tap][oc pad 12]

    const int tid = threadIdx.x;
    for (int i = tid; i < 2400; i += 256) wl[i] = 0.f;
    __syncthreads();
    for (int i = tid; i < 2000; i += 256) {
        const int oc = i / 200, rem = i % 200;   // rem = ic*25+tap
        wl[rem * 12 + oc] = w2[i];
    }

    const int w  = tid & 7;
    const int cp = (tid >> 3) & 3;
    const int pp = tid >> 5;               // 0..7 (2 rows x 4 cols pooled)
    const int pl = pp >> 2, pj = pp & 3;
    const int cy = 2 * pl + (cp >> 1), cx = 2 * pj + (cp & 1);

    // staging: 192 float4, one per thread (tid<192)
    const int sr = tid / 24, sc4 = tid % 24;
    const size_t sOff = ((size_t)(iy0 + sr) * 61 + ix0 + (sc4 >> 1)) * 8 + (sc4 & 1) * 4;
    const bool sact = (tid < 192);

    v2f acc[5];
#pragma unroll
    for (int p = 0; p < 5; ++p) acc[p] = (v2f)(0.f);

    float4 rg;
    {
        const float* hb = h1 + (size_t)b * 8 * 29768;
        if (sact) rg = *reinterpret_cast<const float4*>(hb + sOff);
        if (sact) *reinterpret_cast<float4*>(&tin[tid * 4]) = rg;
    }
    __syncthreads();

    for (int ic = 0; ic < 8; ++ic) {
        if (ic < 7 && sact) {
            const float* hb = h1 + ((size_t)b * 8 + ic + 1) * 29768;
            rg = *reinterpret_cast<const float4*>(hb + sOff);
        }
        for (int kd = 0; kd < 5; ++kd) {
            const float* vrow = &tin[((cy + kd) * 12 + cx) * 8 + w];
            const float* wrow = &wl[(ic * 25 + kd * 5) * 12];
#pragma unroll
            for (int kh = 0; kh < 5; ++kh) {
                const float v = vrow[kh * 8];
                const float4 wa = *reinterpret_cast<const float4*>(&wrow[kh * 12]);
                const float4 wb = *reinterpret_cast<const float4*>(&wrow[kh * 12 + 4]);
                const float2 wc = *reinterpret_cast<const float2*>(&wrow[kh * 12 + 8]);
                const v2f sv = (v2f){v, v};
                pkfma(acc[0], (v2f){wa.x, wa.y}, sv);
                pkfma(acc[1], (v2f){wa.z, wa.w}, sv);
                pkfma(acc[2], (v2f){wb.x, wb.y}, sv);
                pkfma(acc[3], (v2f){wb.z, wb.w}, sv);
                pkfma(acc[4], (v2f){wc.x, wc.y}, sv);
            }
        }
        if (ic < 7) {
            __syncthreads();
            if (sact) *reinterpret_cast<float4*>(&tin[tid * 4]) = rg;
            __syncthreads();
        }
    }

    const int pi = py0 + pl, pjg = px0 + pj;   // always < 28
    const bool doStore = (cp == 0);
#pragma unroll
    for (int p = 0; p < 5; ++p) {
        const float be = b2[2 * p], bo = b2[2 * p + 1];
        float a = acc[p].x, c = acc[p].y;
        a = fmaxf(a, __shfl_xor(a, 8)); a = fmaxf(a, __shfl_xor(a, 16));
        c = fmaxf(c, __shfl_xor(c, 8)); c = fmaxf(c, __shfl_xor(c, 16));
        if (doStore) {
            h2[((((size_t)b * 10 + 2 * p) * 28 + pi) * 28 + pjg) * 8 + w] = fmaxf(a + be, 0.f);
            h2[((((size_t)b * 10 + 2 * p + 1) * 28 + pi) * 28 + pjg) * 8 + w] = fmaxf(c + bo, 0.f);
        }
    }
}

// ---------------- K3: fc1 (62720 -> 32), split-K, partials to ws ----------------
__global__ __launch_bounds__(256) void k_fc1(const float* __restrict__ feat,
                                             const float* __restrict__ w,
                                             float* __restrict__ partials) {
    const int j = blockIdx.x >> 4;
    const int kc = blockIdx.x & 15;
    const int k0 = kc * 3920;
    const float4* w4 = reinterpret_cast<const float4*>(w + (size_t)j * 62720 + k0);
    float acc[8];
#pragma unroll
    for (int b = 0; b < 8; ++b) acc[b] = 0.f;
    for (int i = threadIdx.x; i < 980; i += 256) {
        const float4 wv = w4[i];
#pragma unroll
        for (int b = 0; b < 8; ++b) {
            const float4 fv = *reinterpret_cast<const float4*>(feat + (size_t)b * 62720 + k0 + i * 4);
            acc[b] = fmaf(wv.x, fv.x, fmaf(wv.y, fv.y, fmaf(wv.z, fv.z, fmaf(wv.w, fv.w, acc[b]))));
        }
    }
#pragma unroll
    for (int b = 0; b < 8; ++b)
#pragma unroll
        for (int off = 32; off > 0; off >>= 1) acc[b] += __shfl_down(acc[b], off);
    __shared__ float red[4][8];
    const int wave = threadIdx.x >> 6;
    if ((threadIdx.x & 63) == 0)
#pragma unroll
        for (int b = 0; b < 8; ++b) red[wave][b] = acc[b];
    __syncthreads();
    if (threadIdx.x < 8) {
        partials[(j * 16 + kc) * 8 + threadIdx.x] =
            red[0][threadIdx.x] + red[1][threadIdx.x] + red[2][threadIdx.x] + red[3][threadIdx.x];
    }
}

// ---------------- K4: fc1-reduce + bias/relu + fc2 + tanh + rigid + moved/reg ----------
__global__ __launch_bounds__(1024) void k_fc2_moved(const float* __restrict__ partials,
                                                    const float* __restrict__ f1b,
                                                    const float* __restrict__ w,
                                                    const float* __restrict__ bias,
                                                    const float* __restrict__ pos,
                                                    const float* __restrict__ centers,
                                                    float* __restrict__ rt,
                                                    float* __restrict__ movedOut,
                                                    float* __restrict__ regOut) {
    __shared__ float sfo[256];
    __shared__ float srt[64 * 8];
    __shared__ float red[8][128];
    const int tid = threadIdx.x;
    if (tid < 256) {
        const int b = tid >> 5, j = tid & 31;
        float s = 0.f;
#pragma unroll
        for (int kc = 0; kc < 16; ++kc) s += partials[(j * 16 + kc) * 8 + b];
        sfo[b * 32 + j] = fmaxf(s + f1b[j], 0.f);
    }
    __syncthreads();
    if (tid < 64) {
        const int b = tid >> 3, t = tid & 7;
        const float* f = &sfo[b * 32];
        float th[6];
#pragma unroll
        for (int i = 0; i < 6; ++i) {
            const int o = t * 6 + i;
            float s = bias[o];
            const float* wr = w + o * 32;
#pragma unroll
            for (int k = 0; k < 32; ++k) s = fmaf(f[k], wr[k], s);
            th[i] = tanhf(s);
        }
        float s0, c0, s1, c1, s2, c2;
        sincosf(PI_F * th[0], &s0, &c0);
        sincosf(PI_F * th[1], &s1, &c1);
        sincosf(PI_F * th[2], &s2, &c2);
        const float R00 = c0 * c1, R10 = s0 * c1, R20 = -s1;
        const float R01 = -s0 * c2 + c0 * s1 * s2;
        const float R11 =  c0 * c2 + s0 * s1 * s2;
        const float R21 =  c1 * s2;
        const float T0 = th[3] * 128.f + 64.f - (64.f * R00 + 64.f * R10 + 4.f * R20);
        const float T1 = th[4] * 128.f + 64.f - (64.f * R01 + 64.f * R11 + 4.f * R21);
        float* o = srt + tid * 8;
        o[0] = R00; o[1] = R10; o[2] = R20; o[3] = T0;
        o[4] = R01; o[5] = R11; o[6] = R21; o[7] = T1;
        float* og = rt + tid * 8;
        og[0] = R00; og[1] = R10; og[2] = R20; og[3] = T0;
        og[4] = R01; og[5] = R11; og[6] = R21; og[7] = T1;
    }
    __syncthreads();
    const int b = tid >> 7, p = tid & 127;
    float nrm = 0.f;
    if (p < 100) {
        const float* pp = pos + ((size_t)b * 100 + p) * 3;
        const float p0 = pp[0], p1 = pp[1], p2 = pp[2];
        int i0 = (int)rintf(p0); i0 = i0 < 0 ? 0 : (i0 > 127 ? 127 : i0);
        int i1 = (int)rintf(p1); i1 = i1 < 0 ? 0 : (i1 > 127 ? 127 : i1);
        int i2 = (int)rintf(p2); i2 = i2 < 0 ? 0 : (i2 > 7 ? 7 : i2);
        const float gi = (float)i0, gj = (float)i1, gk = (float)i2;
        const float tsx[8] = {32.f, 32.f, 96.f, 96.f, 32.f, 96.f, 64.f, 64.f};
        const float tsy[8] = {32.f, 96.f, 32.f, 96.f, 64.f, 64.f, 32.f, 96.f};
        float u0 = 0.f, u1 = 0.f, es = 0.f;
#pragma unroll
        for (int t = 0; t < 8; ++t) {
            float dx = gi - tsx[t], dy = gj - tsy[t], dz = gk - 4.f;
            float d = sqrtf(dx * dx + dy * dy + dz * dz);
            float e = expf(-d / 10.f);
            const float* r = srt + (b * 8 + t) * 8;
            float f0 = fmaf(gi, r[0], fmaf(gj, r[1], fmaf(gk, r[2], r[3])));
            float f1 = fmaf(gi, r[4], fmaf(gj, r[5], fmaf(gk, r[6], r[7])));
            u0 = fmaf(e, f0, u0);
            u1 = fmaf(e, f1, u1);
            es += e;
        }
        const float inv = 1.f / es;
        const float nf0 = (u0 * inv) * (1.f / 64.f) - 1.f;
        const float nf1 = (u1 * inv) * (1.f / 64.f) - 1.f;
        const float m0 = 2.f * p0 - (0.5f + 0.5f * nf0) * 127.f;
        const float m1 = 2.f * p1 - (0.5f + 0.5f * nf1) * 127.f;
        const float m2 = 2.f * p2 - 3.5f;
        float* mo = movedOut + ((size_t)b * 100 + p) * 3;
        mo[0] = m0; mo[1] = m1; mo[2] = m2;
        const float* ce = centers + p * 3;
        const float d0 = m0 - ce[0], d1 = m1 - ce[1], d2 = m2 - ce[2];
        nrm = sqrtf(d0 * d0 + d1 * d1 + d2 * d2);
    }
    red[b][p] = nrm;
    __syncthreads();
    for (int s = 64; s > 0; s >>= 1) {
        if (p < s) red[b][p] += red[b][p + s];
        __syncthreads();
    }
    if (p == 0) regOut[b] = red[b][0] * 0.01f;
}

// ---------------- K5: flow field + grid output + trilinear grid-sample (fused) ----------
__global__ __launch_bounds__(256) void k_flow_sample(const float* __restrict__ x,
                                                     const float* __restrict__ rt,
                                                     float* __restrict__ outXt,
                                                     float* __restrict__ outGrid) {
    const int b = blockIdx.y;
    const int l = blockIdx.x * 256 + threadIdx.x;   // voxel index, 131072 per batch
    __shared__ float srt[64];
    __shared__ float sg[768];
    if (threadIdx.x < 64) srt[threadIdx.x] = rt[b * 64 + threadIdx.x];
    __syncthreads();

    const float gi = (float)(l >> 10);
    const float gj = (float)((l >> 3) & 127);
    const float gk = (float)(l & 7);

    const float tsx[8] = {32.f, 32.f, 96.f, 96.f, 32.f, 96.f, 64.f, 64.f};
    const float tsy[8] = {32.f, 96.f, 32.f, 96.f, 64.f, 64.f, 32.f, 96.f};

    float u0 = 0.f, u1 = 0.f, es = 0.f;
#pragma unroll
    for (int t = 0; t < 8; ++t) {
        float dx = gi - tsx[t], dy = gj - tsy[t], dz = gk - 4.f;
        float d = sqrtf(dx * dx + dy * dy + dz * dz);
        float e = expf(-d / 10.f);
        const float4 ra = *reinterpret_cast<const float4*>(&srt[t * 8]);
        const float4 rb = *reinterpret_cast<const float4*>(&srt[t * 8 + 4]);
        float f0 = fmaf(gi, ra.x, fmaf(gj, ra.y, fmaf(gk, ra.z, ra.w)));
        float f1 = fmaf(gi, rb.x, fmaf(gj, rb.y, fmaf(gk, rb.z, rb.w)));
        u0 = fmaf(e, f0, u0);
        u1 = fmaf(e, f1, u1);
        es += e;
    }
    const float inv = 1.f / es;
    const float fs0 = u0 * inv, fs1 = u1 * inv;
    const float nf0 = fs0 * (1.f / 64.f) - 1.f;
    const float nf1 = fs1 * (1.f / 64.f) - 1.f;

    // coalesced grid store via LDS transpose
    sg[threadIdx.x * 3 + 0] = 0.f;
    sg[threadIdx.x * 3 + 1] = nf1;
    sg[threadIdx.x * 3 + 2] = nf0;
    __syncthreads();
    if (threadIdx.x < 192) {
        *reinterpret_cast<float4*>(outGrid + (size_t)b * 393216 + (size_t)blockIdx.x * 768 +
                                   threadIdx.x * 4) = *reinterpret_cast<float4*>(&sg[threadIdx.x * 4]);
    }

    const float iz = fs0 - 0.5f, iy = fs1 - 0.5f;
    const float z0f = floorf(iz), y0f = floorf(iy);
    const float fz = iz - z0f, fy = iy - y0f;
    const int z0 = (int)z0f, y0 = (int)y0f;
    float s0 = 0.f, s1 = 0.f, s2 = 0.f, s3 = 0.f;
    const float* xb = x + (size_t)b * 4 * 131072;
#pragma unroll
    for (int dz = 0; dz < 2; ++dz) {
        const int zc = z0 + dz;
        if (zc < 0 || zc > 127) continue;
        const float wz = dz ? fz : 1.f - fz;
#pragma unroll
        for (int dy = 0; dy < 2; ++dy) {
            const int yc = y0 + dy;
            if (yc < 0 || yc > 127) continue;
            const float wv = wz * (dy ? fy : 1.f - fy) * 0.5f;
            const float* p = xb + ((size_t)zc * 128 + yc) * 8 + 3;
            s0 = fmaf(wv, p[0] + p[1], s0);
            s1 = fmaf(wv, p[131072] + p[131073], s1);
            s2 = fmaf(wv, p[262144] + p[262145], s2);
            s3 = fmaf(wv, p[393216] + p[393217], s3);
        }
    }
    float* o = outXt + (size_t)b * 4 * 131072 + l;
    o[0] = s0; o[131072] = s1; o[262144] = s2; o[393216] = s3;
}

// ---------------- launch ----------------
extern "C" void kernel_launch(void* const* d_in, const int* in_sizes, int n_in,
                              void* d_out, int out_size, void* d_ws, size_t ws_size,
                              hipStream_t stream) {
    const float* x       = (const float*)d_in[0];
    const float* pos     = (const float*)d_in[1];
    const float* centers = (const float*)d_in[2];
    const float* c1w     = (const float*)d_in[3];
    const float* c1b     = (const float*)d_in[4];
    const float* c2w     = (const float*)d_in[5];
    const float* c2b     = (const float*)d_in[6];
    const float* f1w     = (const float*)d_in[7];
    const float* f1b     = (const float*)d_in[8];
    const float* f2w     = (const float*)d_in[9];
    const float* f2b     = (const float*)d_in[10];

    float* out = (float*)d_out;
    float* ws  = (float*)d_ws;

    // workspace layout (floats)
    float* h1       = ws;                      // 8*8*61*61*8   = 1,905,152
    float* h2       = h1 + 1905152;            // 8*10*28*28*8  =   501,760
    float* partials = h2 + 501760;             // 32*16*8       =     4,096
    float* rt       = partials + 4096;         // 8*8*8         =       512

    // output layout (floats): X_t | grid | reg | moved
    float* outXt    = out;                         // 4,194,304
    float* outGrid  = out + 4194304;               // 3,145,728
    float* outReg   = out + 4194304 + 3145728;     // 8
    float* outMoved = outReg + 8;                  // 2,400

    k_conv1<<<dim3(128, 8), 256, 0, stream>>>(x, c1w, c1b, h1);
    k_conv2<<<dim3(98, 8), 256, 0, stream>>>(h1, c2w, c2b, h2);
    k_fc1<<<512, 256, 0, stream>>>(h2, f1w, partials);
    k_fc2_moved<<<1, 1024, 0, stream>>>(partials, f1b, f2w, f2b, pos, centers, rt, outMoved, outReg);
    k_flow_sample<<<dim3(512, 8), 256, 0, stream>>>(x, rt, outXt, outGrid);
}

// Round 5
// 101.594 us; speedup vs baseline: 1.1610x; 1.1610x over previous
//
#include <hip/hip_runtime.h>

#define PI_F 3.14159265358979323846f

typedef float v2f __attribute__((ext_vector_type(2)));
typedef float v4f __attribute__((ext_vector_type(4)));

// acc.x += w.x*v.x; acc.y += w.y*v.x   (broadcast v.lo via op_sel)
__device__ __forceinline__ void pkfma_lo(v2f& d, v2f w, v2f v) {
    asm("v_pk_fma_f32 %0, %1, %2, %0 op_sel:[0,0,0] op_sel_hi:[1,0,1]"
        : "+v"(d) : "v"(w), "v"(v));
}
// acc.x += w.x*v.y; acc.y += w.y*v.y   (broadcast v.hi via op_sel)
__device__ __forceinline__ void pkfma_hi(v2f& d, v2f w, v2f v) {
    asm("v_pk_fma_f32 %0, %1, %2, %0 op_sel:[0,1,0] op_sel_hi:[1,1,1]"
        : "+v"(d) : "v"(w), "v"(v));
}

// ---------------- K1: conv1 7x7 (4->8) + maxpool 2x2 + bias + relu ----------------
// x:(8,4,128,128,8) -> h1:(8,8,61,61,8).
// Tile 8x4 pooled; thread=(pp32,cp4,wq2). acc v2f[4 ocpair][4 w].
// tin rows padded to 35 float4 (560B == 48 mod 128 -> uniform 4 lanes/16B slot, conflict-free).
__global__ __launch_bounds__(256, 6) void k_conv1(const float* __restrict__ x,
                                                  const float* __restrict__ w1,
                                                  const float* __restrict__ b1,
                                                  float* __restrict__ h1) {
    const int b = blockIdx.y;
    const int ty = blockIdx.x >> 4, tx = blockIdx.x & 15;   // 8 x 16 tiles
    const int py0 = ty * 8, px0 = tx * 4;
    const int iy0 = py0 * 2, ix0 = px0 * 2;

    __shared__ float tin[22 * 140];        // 22 rows x 35 f4 (28 data + 7 pad) = 12320 B
    __shared__ float wl[4 * 49 * 8];       // [ic][tap][oc]

    const int tid = threadIdx.x;
    for (int i = tid; i < 1568; i += 256) {
        const int oc = i / 196, rem = i % 196;        // rem = ic*49+tap
        wl[rem * 8 + oc] = w1[i];
    }

    const int wq = tid & 1;
    const int cp = (tid >> 1) & 3;
    const int pp = tid >> 3;
    const int pl = pp >> 2, pj = pp & 3;
    const int cy = 2 * pl + (cp >> 1), cx = 2 * pj + (cp & 1);

    // staging: 616 data float4 (22 rows x 28); LDS f4 index = r*35 + c4
    int sIdx[3];
    sIdx[0] = tid; sIdx[1] = tid + 256; sIdx[2] = (tid + 512 < 616) ? tid + 512 : 615;
    const bool s2act = (tid + 512 < 616);
    size_t sOff[3];
    int sLds[3];
#pragma unroll
    for (int s = 0; s < 3; ++s) {
        const int r = sIdx[s] / 28, c4 = sIdx[s] % 28;
        const int row = min(iy0 + r, 127), col = min(ix0 + (c4 >> 1), 127);
        sOff[s] = ((size_t)row * 128 + col) * 8 + (c4 & 1) * 4;
        sLds[s] = (r * 35 + c4) * 4;
    }

    v2f acc[4][4];
#pragma unroll
    for (int p = 0; p < 4; ++p)
#pragma unroll
        for (int w = 0; w < 4; ++w) acc[p][w] = (v2f)(0.f);

    float4 r0, r1, r2;
    {
        const float* xb = x + (size_t)b * 4 * 131072;
        r0 = *reinterpret_cast<const float4*>(xb + sOff[0]);
        r1 = *reinterpret_cast<const float4*>(xb + sOff[1]);
        r2 = *reinterpret_cast<const float4*>(xb + sOff[2]);
        *reinterpret_cast<float4*>(&tin[sLds[0]]) = r0;
        *reinterpret_cast<float4*>(&tin[sLds[1]]) = r1;
        if (s2act) *reinterpret_cast<float4*>(&tin[sLds[2]]) = r2;
    }
    __syncthreads();

    for (int ic = 0; ic < 4; ++ic) {
        if (ic < 3) {
            const float* xb = x + ((size_t)b * 4 + ic + 1) * 131072;
            r0 = *reinterpret_cast<const float4*>(xb + sOff[0]);
            r1 = *reinterpret_cast<const float4*>(xb + sOff[1]);
            r2 = *reinterpret_cast<const float4*>(xb + sOff[2]);
        }
        for (int kd = 0; kd < 7; ++kd) {
            const float* vrow = &tin[(cy + kd) * 140 + cx * 8 + wq * 4];
            const float* wrow = &wl[(ic * 49 + kd * 7) * 8];
#pragma unroll
            for (int kh = 0; kh < 7; ++kh) {
                const v4f vq = *reinterpret_cast<const v4f*>(vrow + kh * 8);
                const v4f wa = *reinterpret_cast<const v4f*>(wrow + kh * 8);
                const v4f wb = *reinterpret_cast<const v4f*>(wrow + kh * 8 + 4);
                const v2f v01 = __builtin_shufflevector(vq, vq, 0, 1);
                const v2f v23 = __builtin_shufflevector(vq, vq, 2, 3);
                v2f wp[4];
                wp[0] = __builtin_shufflevector(wa, wa, 0, 1);
                wp[1] = __builtin_shufflevector(wa, wa, 2, 3);
                wp[2] = __builtin_shufflevector(wb, wb, 0, 1);
                wp[3] = __builtin_shufflevector(wb, wb, 2, 3);
#pragma unroll
                for (int p = 0; p < 4; ++p) {
                    pkfma_lo(acc[p][0], wp[p], v01);
                    pkfma_hi(acc[p][1], wp[p], v01);
                    pkfma_lo(acc[p][2], wp[p], v23);
                    pkfma_hi(acc[p][3], wp[p], v23);
                }
            }
        }
        if (ic < 3) {
            __syncthreads();
            *reinterpret_cast<float4*>(&tin[sLds[0]]) = r0;
            *reinterpret_cast<float4*>(&tin[sLds[1]]) = r1;
            if (s2act) *reinterpret_cast<float4*>(&tin[sLds[2]]) = r2;
            __syncthreads();
        }
    }

    const int pi = py0 + pl, pjg = px0 + pj;
    const bool doStore = (cp == 0) && (pi < 61) && (pjg < 61);
#pragma unroll
    for (int p = 0; p < 4; ++p) {
        const float be = b1[2 * p], bo = b1[2 * p + 1];
        float e[4], o[4];
#pragma unroll
        for (int w = 0; w < 4; ++w) {
            float a = acc[p][w].x, c = acc[p][w].y;
            a = fmaxf(a, __shfl_xor(a, 2)); a = fmaxf(a, __shfl_xor(a, 4));
            c = fmaxf(c, __shfl_xor(c, 2)); c = fmaxf(c, __shfl_xor(c, 4));
            e[w] = fmaxf(a + be, 0.f);
            o[w] = fmaxf(c + bo, 0.f);
        }
        if (doStore) {
            *reinterpret_cast<float4*>(
                h1 + ((((size_t)b * 8 + 2 * p) * 61 + pi) * 61 + pjg) * 8 + wq * 4) =
                make_float4(e[0], e[1], e[2], e[3]);
            *reinterpret_cast<float4*>(
                h1 + ((((size_t)b * 8 + 2 * p + 1) * 61 + pi) * 61 + pjg) * 8 + wq * 4) =
                make_float4(o[0], o[1], o[2], o[3]);
        }
    }
}

// ---------------- K2: conv2 5x5 (8->10) + maxpool 2x2 + bias + relu ----------------
// h1:(8,8,61,61,8) -> h2:(8,10,28,28,8).
// Block: tile 2x4 pooled, 4 waves, ic split 2/wave; all 8 ic tiles staged up front.
// tin rows 27 f4 (24 data + 3 pad, 432B == 48 mod 128 -> conflict-free).
__global__ __launch_bounds__(256, 4) void k_conv2(const float* __restrict__ h1,
                                                  const float* __restrict__ w2,
                                                  const float* __restrict__ b2,
                                                  float* __restrict__ h2) {
    const int b = blockIdx.y;
    const int ty = blockIdx.x / 7, tx = blockIdx.x % 7;    // 14 x 7 tiles
    const int py0 = ty * 2, px0 = tx * 4;
    const int iy0 = py0 * 2, ix0 = px0 * 2;

    __shared__ float smem[9312];   // [0..6911] tin: 8 ic x (8 rows x 27 f4); [6912..9311] wl
    float* wl = &smem[6912];       // [ic][tap][oc pad 12]

    const int tid = threadIdx.x;
    for (int i = tid; i < 2000; i += 256) {
        const int oc = i / 200, rem = i % 200;   // rem = ic*25+tap
        wl[rem * 12 + oc] = w2[i];
    }
    // stage all 8 ic tiles: 8 x 192 data f4
    {
        const float* hb = h1 + (size_t)b * 8 * 29768;
#pragma unroll
        for (int k = 0; k < 6; ++k) {
            const int s = tid + k * 256;            // < 1536
            const int ic = s / 192, rem = s % 192;
            const int r = rem / 24, c4 = rem % 24;
            const float4 v = *reinterpret_cast<const float4*>(
                hb + (size_t)ic * 29768 + ((size_t)(iy0 + r) * 61 + ix0 + (c4 >> 1)) * 8 + (c4 & 1) * 4);
            *reinterpret_cast<float4*>(&smem[(ic * 216 + r * 27 + c4) * 4]) = v;
        }
    }
    __syncthreads();

    const int wave = tid >> 6, lane = tid & 63;
    const int wq = lane & 1;
    const int cp = (lane >> 1) & 3;
    const int pp = lane >> 3;              // 0..7 (2 rows x 4 cols pooled)
    const int pl = pp >> 2, pj = pp & 3;
    const int cy = 2 * pl + (cp >> 1), cx = 2 * pj + (cp & 1);

    v2f acc[5][4];
#pragma unroll
    for (int p = 0; p < 5; ++p)
#pragma unroll
        for (int w = 0; w < 4; ++w) acc[p][w] = (v2f)(0.f);

#pragma unroll
    for (int ic2 = 0; ic2 < 2; ++ic2) {
        const int ic = 2 * wave + ic2;
        for (int kd = 0; kd < 5; ++kd) {
            const float* vrow = &smem[ic * 864 + (cy + kd) * 108 + cx * 8 + wq * 4];
            const float* wrow = &wl[(ic * 25 + kd * 5) * 12];
#pragma unroll
            for (int kh = 0; kh < 5; ++kh) {
                const v4f vq = *reinterpret_cast<const v4f*>(vrow + kh * 8);
                const v4f wa = *reinterpret_cast<const v4f*>(wrow + kh * 12);
                const v4f wb = *reinterpret_cast<const v4f*>(wrow + kh * 12 + 4);
                const v2f wc = *reinterpret_cast<const v2f*>(wrow + kh * 12 + 8);
                const v2f v01 = __builtin_shufflevector(vq, vq, 0, 1);
                const v2f v23 = __builtin_shufflevector(vq, vq, 2, 3);
                v2f wp[5];
                wp[0] = __builtin_shufflevector(wa, wa, 0, 1);
                wp[1] = __builtin_shufflevector(wa, wa, 2, 3);
                wp[2] = __builtin_shufflevector(wb, wb, 0, 1);
                wp[3] = __builtin_shufflevector(wb, wb, 2, 3);
                wp[4] = wc;
#pragma unroll
                for (int p = 0; p < 5; ++p) {
                    pkfma_lo(acc[p][0], wp[p], v01);
                    pkfma_hi(acc[p][1], wp[p], v01);
                    pkfma_lo(acc[p][2], wp[p], v23);
                    pkfma_hi(acc[p][3], wp[p], v23);
                }
            }
        }
    }
    __syncthreads();
    // cross-wave reduction: waves 1..3 dump 40 floats each into smem[0..7679]
    if (wave > 0) {
        float* dst = &smem[((wave - 1) * 64 + lane) * 40];
#pragma unroll
        for (int p = 0; p < 5; ++p)
#pragma unroll
            for (int w = 0; w < 4; ++w)
                *reinterpret_cast<v2f*>(dst + (p * 4 + w) * 2) = acc[p][w];
    }
    __syncthreads();
    if (wave == 0) {
#pragma unroll
        for (int v = 0; v < 3; ++v) {
            const float* src = &smem[(v * 64 + lane) * 40];
#pragma unroll
            for (int p = 0; p < 5; ++p)
#pragma unroll
                for (int w = 0; w < 4; ++w)
                    acc[p][w] += *reinterpret_cast<const v2f*>(src + (p * 4 + w) * 2);
        }
        const int pi = py0 + pl, pjg = px0 + pj;
        const bool doStore = (cp == 0);
#pragma unroll
        for (int p = 0; p < 5; ++p) {
            const float be = b2[2 * p], bo = b2[2 * p + 1];
            float e[4], o[4];
#pragma unroll
            for (int w = 0; w < 4; ++w) {
                float a = acc[p][w].x, c = acc[p][w].y;
                a = fmaxf(a, __shfl_xor(a, 2)); a = fmaxf(a, __shfl_xor(a, 4));
                c = fmaxf(c, __shfl_xor(c, 2)); c = fmaxf(c, __shfl_xor(c, 4));
                e[w] = fmaxf(a + be, 0.f);
                o[w] = fmaxf(c + bo, 0.f);
            }
            if (doStore) {
                *reinterpret_cast<float4*>(
                    h2 + ((((size_t)b * 10 + 2 * p) * 28 + pi) * 28 + pjg) * 8 + wq * 4) =
                    make_float4(e[0], e[1], e[2], e[3]);
                *reinterpret_cast<float4*>(
                    h2 + ((((size_t)b * 10 + 2 * p + 1) * 28 + pi) * 28 + pjg) * 8 + wq * 4) =
                    make_float4(o[0], o[1], o[2], o[3]);
            }
        }
    }
}

// ---------------- K3: fc1 (62720 -> 32), split-K, partials to ws ----------------
__global__ __launch_bounds__(256) void k_fc1(const float* __restrict__ feat,
                                             const float* __restrict__ w,
                                             float* __restrict__ partials) {
    const int j = blockIdx.x >> 4;
    const int kc = blockIdx.x & 15;
    const int k0 = kc * 3920;
    const float4* w4 = reinterpret_cast<const float4*>(w + (size_t)j * 62720 + k0);
    float acc[8];
#pragma unroll
    for (int b = 0; b < 8; ++b) acc[b] = 0.f;
    for (int i = threadIdx.x; i < 980; i += 256) {
        const float4 wv = w4[i];
#pragma unroll
        for (int b = 0; b < 8; ++b) {
            const float4 fv = *reinterpret_cast<const float4*>(feat + (size_t)b * 62720 + k0 + i * 4);
            acc[b] = fmaf(wv.x, fv.x, fmaf(wv.y, fv.y, fmaf(wv.z, fv.z, fmaf(wv.w, fv.w, acc[b]))));
        }
    }
#pragma unroll
    for (int b = 0; b < 8; ++b)
#pragma unroll
        for (int off = 32; off > 0; off >>= 1) acc[b] += __shfl_down(acc[b], off);
    __shared__ float red[4][8];
    const int wave = threadIdx.x >> 6;
    if ((threadIdx.x & 63) == 0)
#pragma unroll
        for (int b = 0; b < 8; ++b) red[wave][b] = acc[b];
    __syncthreads();
    if (threadIdx.x < 8) {
        partials[(j * 16 + kc) * 8 + threadIdx.x] =
            red[0][threadIdx.x] + red[1][threadIdx.x] + red[2][threadIdx.x] + red[3][threadIdx.x];
    }
}

// ---------------- K4: fc1-reduce + bias/relu + fc2 + tanh + rigid + moved/reg ----------
__global__ __launch_bounds__(1024) void k_fc2_moved(const float* __restrict__ partials,
                                                    const float* __restrict__ f1b,
                                                    const float* __restrict__ w,
                                                    const float* __restrict__ bias,
                                                    const float* __restrict__ pos,
                                                    const float* __restrict__ centers,
                                                    float* __restrict__ rt,
                                                    float* __restrict__ movedOut,
                                                    float* __restrict__ regOut) {
    __shared__ float sfo[256];
    __shared__ float srt[64 * 8];
    __shared__ float red[8][128];
    const int tid = threadIdx.x;
    if (tid < 256) {
        const int b = tid >> 5, j = tid & 31;
        float s = 0.f;
#pragma unroll
        for (int kc = 0; kc < 16; ++kc) s += partials[(j * 16 + kc) * 8 + b];
        sfo[b * 32 + j] = fmaxf(s + f1b[j], 0.f);
    }
    __syncthreads();
    if (tid < 64) {
        const int b = tid >> 3, t = tid & 7;
        const float* f = &sfo[b * 32];
        float th[6];
#pragma unroll
        for (int i = 0; i < 6; ++i) {
            const int o = t * 6 + i;
            float s = bias[o];
            const float* wr = w + o * 32;
#pragma unroll
            for (int k = 0; k < 32; ++k) s = fmaf(f[k], wr[k], s);
            th[i] = tanhf(s);
        }
        float s0, c0, s1, c1, s2, c2;
        sincosf(PI_F * th[0], &s0, &c0);
        sincosf(PI_F * th[1], &s1, &c1);
        sincosf(PI_F * th[2], &s2, &c2);
        const float R00 = c0 * c1, R10 = s0 * c1, R20 = -s1;
        const float R01 = -s0 * c2 + c0 * s1 * s2;
        const float R11 =  c0 * c2 + s0 * s1 * s2;
        const float R21 =  c1 * s2;
        const float T0 = th[3] * 128.f + 64.f - (64.f * R00 + 64.f * R10 + 4.f * R20);
        const float T1 = th[4] * 128.f + 64.f - (64.f * R01 + 64.f * R11 + 4.f * R21);
        float* o = srt + tid * 8;
        o[0] = R00; o[1] = R10; o[2] = R20; o[3] = T0;
        o[4] = R01; o[5] = R11; o[6] = R21; o[7] = T1;
        float* og = rt + tid * 8;
        og[0] = R00; og[1] = R10; og[2] = R20; og[3] = T0;
        og[4] = R01; og[5] = R11; og[6] = R21; og[7] = T1;
    }
    __syncthreads();
    const int b = tid >> 7, p = tid & 127;
    float nrm = 0.f;
    if (p < 100) {
        const float* pp = pos + ((size_t)b * 100 + p) * 3;
        const float p0 = pp[0], p1 = pp[1], p2 = pp[2];
        int i0 = (int)rintf(p0); i0 = i0 < 0 ? 0 : (i0 > 127 ? 127 : i0);
        int i1 = (int)rintf(p1); i1 = i1 < 0 ? 0 : (i1 > 127 ? 127 : i1);
        int i2 = (int)rintf(p2); i2 = i2 < 0 ? 0 : (i2 > 7 ? 7 : i2);
        const float gi = (float)i0, gj = (float)i1, gk = (float)i2;
        const float tsx[8] = {32.f, 32.f, 96.f, 96.f, 32.f, 96.f, 64.f, 64.f};
        const float tsy[8] = {32.f, 96.f, 32.f, 96.f, 64.f, 64.f, 32.f, 96.f};
        float u0 = 0.f, u1 = 0.f, es = 0.f;
#pragma unroll
        for (int t = 0; t < 8; ++t) {
            float dx = gi - tsx[t], dy = gj - tsy[t], dz = gk - 4.f;
            float d = sqrtf(dx * dx + dy * dy + dz * dz);
            float e = expf(-d / 10.f);
            const float* r = srt + (b * 8 + t) * 8;
            float f0 = fmaf(gi, r[0], fmaf(gj, r[1], fmaf(gk, r[2], r[3])));
            float f1 = fmaf(gi, r[4], fmaf(gj, r[5], fmaf(gk, r[6], r[7])));
            u0 = fmaf(e, f0, u0);
            u1 = fmaf(e, f1, u1);
            es += e;
        }
        const float inv = 1.f / es;
        const float nf0 = (u0 * inv) * (1.f / 64.f) - 1.f;
        const float nf1 = (u1 * inv) * (1.f / 64.f) - 1.f;
        const float m0 = 2.f * p0 - (0.5f + 0.5f * nf0) * 127.f;
        const float m1 = 2.f * p1 - (0.5f + 0.5f * nf1) * 127.f;
        const float m2 = 2.f * p2 - 3.5f;
        float* mo = movedOut + ((size_t)b * 100 + p) * 3;
        mo[0] = m0; mo[1] = m1; mo[2] = m2;
        const float* ce = centers + p * 3;
        const float d0 = m0 - ce[0], d1 = m1 - ce[1], d2 = m2 - ce[2];
        nrm = sqrtf(d0 * d0 + d1 * d1 + d2 * d2);
    }
    red[b][p] = nrm;
    __syncthreads();
    for (int s = 64; s > 0; s >>= 1) {
        if (p < s) red[b][p] += red[b][p + s];
        __syncthreads();
    }
    if (p == 0) regOut[b] = red[b][0] * 0.01f;
}

// ---------------- K5: flow field + grid output + trilinear grid-sample (fused) ----------
__global__ __launch_bounds__(256) void k_flow_sample(const float* __restrict__ x,
                                                     const float* __restrict__ rt,
                                                     float* __restrict__ outXt,
                                                     float* __restrict__ outGrid) {
    const int b = blockIdx.y;
    const int l = blockIdx.x * 256 + threadIdx.x;   // voxel index, 131072 per batch
    __shared__ float srt[64];
    __shared__ float sg[768];
    if (threadIdx.x < 64) srt[threadIdx.x] = rt[b * 64 + threadIdx.x];
    __syncthreads();

    const float gi = (float)(l >> 10);
    const float gj = (float)((l >> 3) & 127);
    const float gk = (float)(l & 7);

    const float tsx[8] = {32.f, 32.f, 96.f, 96.f, 32.f, 96.f, 64.f, 64.f};
    const float tsy[8] = {32.f, 96.f, 32.f, 96.f, 64.f, 64.f, 32.f, 96.f};

    float u0 = 0.f, u1 = 0.f, es = 0.f;
#pragma unroll
    for (int t = 0; t < 8; ++t) {
        float dx = gi - tsx[t], dy = gj - tsy[t], dz = gk - 4.f;
        float d = sqrtf(dx * dx + dy * dy + dz * dz);
        float e = expf(-d / 10.f);
        const float4 ra = *reinterpret_cast<const float4*>(&srt[t * 8]);
        const float4 rb = *reinterpret_cast<const float4*>(&srt[t * 8 + 4]);
        float f0 = fmaf(gi, ra.x, fmaf(gj, ra.y, fmaf(gk, ra.z, ra.w)));
        float f1 = fmaf(gi, rb.x, fmaf(gj, rb.y, fmaf(gk, rb.z, rb.w)));
        u0 = fmaf(e, f0, u0);
        u1 = fmaf(e, f1, u1);
        es += e;
    }
    const float inv = 1.f / es;
    const float fs0 = u0 * inv, fs1 = u1 * inv;
    const float nf0 = fs0 * (1.f / 64.f) - 1.f;
    const float nf1 = fs1 * (1.f / 64.f) - 1.f;

    // coalesced grid store via LDS transpose
    sg[threadIdx.x * 3 + 0] = 0.f;
    sg[threadIdx.x * 3 + 1] = nf1;
    sg[threadIdx.x * 3 + 2] = nf0;
    __syncthreads();
    if (threadIdx.x < 192) {
        *reinterpret_cast<float4*>(outGrid + (size_t)b * 393216 + (size_t)blockIdx.x * 768 +
                                   threadIdx.x * 4) = *reinterpret_cast<float4*>(&sg[threadIdx.x * 4]);
    }

    const float iz = fs0 - 0.5f, iy = fs1 - 0.5f;
    const float z0f = floorf(iz), y0f = floorf(iy);
    const float fz = iz - z0f, fy = iy - y0f;
    const int z0 = (int)z0f, y0 = (int)y0f;
    float s0 = 0.f, s1 = 0.f, s2 = 0.f, s3 = 0.f;
    const float* xb = x + (size_t)b * 4 * 131072;
#pragma unroll
    for (int dz = 0; dz < 2; ++dz) {
        const int zc = z0 + dz;
        if (zc < 0 || zc > 127) continue;
        const float wz = dz ? fz : 1.f - fz;
#pragma unroll
        for (int dy = 0; dy < 2; ++dy) {
            const int yc = y0 + dy;
            if (yc < 0 || yc > 127) continue;
            const float wv = wz * (dy ? fy : 1.f - fy) * 0.5f;
            const float* p = xb + ((size_t)zc * 128 + yc) * 8 + 3;
            s0 = fmaf(wv, p[0] + p[1], s0);
            s1 = fmaf(wv, p[131072] + p[131073], s1);
            s2 = fmaf(wv, p[262144] + p[262145], s2);
            s3 = fmaf(wv, p[393216] + p[393217], s3);
        }
    }
    float* o = outXt + (size_t)b * 4 * 131072 + l;
    o[0] = s0; o[131072] = s1; o[262144] = s2; o[393216] = s3;
}

// ---------------- launch ----------------
extern "C" void kernel_launch(void* const* d_in, const int* in_sizes, int n_in,
                              void* d_out, int out_size, void* d_ws, size_t ws_size,
                              hipStream_t stream) {
    const float* x       = (const float*)d_in[0];
    const float* pos     = (const float*)d_in[1];
    const float* centers = (const float*)d_in[2];
    const float* c1w     = (const float*)d_in[3];
    const float* c1b     = (const float*)d_in[4];
    const float* c2w     = (const float*)d_in[5];
    const float* c2b     = (const float*)d_in[6];
    const float* f1w     = (const float*)d_in[7];
    const float* f1b     = (const float*)d_in[8];
    const float* f2w     = (const float*)d_in[9];
    const float* f2b     = (const float*)d_in[10];

    float* out = (float*)d_out;
    float* ws  = (float*)d_ws;

    // workspace layout (floats)
    float* h1       = ws;                      // 8*8*61*61*8   = 1,905,152
    float* h2       = h1 + 1905152;            // 8*10*28*28*8  =   501,760
    float* partials = h2 + 501760;             // 32*16*8       =     4,096
    float* rt       = partials + 4096;         // 8*8*8         =       512

    // output layout (floats): X_t | grid | reg | moved
    float* outXt    = out;                         // 4,194,304
    float* outGrid  = out + 4194304;               // 3,145,728
    float* outReg   = out + 4194304 + 3145728;     // 8
    float* outMoved = outReg + 8;                  // 2,400

    k_conv1<<<dim3(128, 8), 256, 0, stream>>>(x, c1w, c1b, h1);
    k_conv2<<<dim3(98, 8), 256, 0, stream>>>(h1, c2w, c2b, h2);
    k_fc1<<<512, 256, 0, stream>>>(h2, f1w, partials);
    k_fc2_moved<<<1, 1024, 0, stream>>>(partials, f1b, f2w, f2b, pos, centers, rt, outMoved, outReg);
    k_flow_sample<<<dim3(512, 8), 256, 0, stream>>>(x, rt, outXt, outGrid);
}